// Round 9
// baseline (51.955 us; speedup 1.0000x reference)
//
#include <hip/hip_runtime.h>

#define BN 4
#define C 256
#define H 64
#define W 64
#define CM 64
#define G 16
#define GC 16
#define KS 7
#define K2 49
#define PADD 3
#define EPSV 1e-5f

#define TS 16
#define HSLOT_U 388   // per-channel halo slab stride in u32 (22 rows * 16 + pad)

// workspace layout (float offsets)
#define W1T_OFF 0                       // [256][64] w1T[c][o]
#define B2P_OFF (W1T_OFF + C*CM)        // [16][64] padded bias
#define S1_OFF  (B2P_OFF + G*64)
#define B1_OFF  (S1_OFF + CM)
#define S2_OFF  (B1_OFF + CM)
#define B2C_OFF (S2_OFF + C)
#define ZERO_OFF (B2C_OFF + C)          // [16] zeros
#define ABF_OFF (ZERO_OFF + 16)         // ushort: A-frags 16g*4mt*2ks*64lane*8
#define TBF_OFF (ABF_OFF + 32768)       // ushort: t bf16 [4][16tile][256pix][64o]
#define XBF_OFF (TBF_OFF + 524288)      // ushort: x bf16 [4][256][64][64]

typedef __attribute__((ext_vector_type(8))) short bf16x8;
typedef __attribute__((ext_vector_type(4))) float f32x4;

__device__ __forceinline__ uint f2bf_rne(float f) {
  uint u = __float_as_uint(f);
  return (u + 0x7fffu + ((u >> 16) & 1u)) >> 16;
}

__device__ __forceinline__ void gload_lds4(const void* g, void* l) {
  __builtin_amdgcn_global_load_lds(
      (const __attribute__((address_space(1))) void*)g,
      (__attribute__((address_space(3))) void*)l, 4, 0, 0);
}

__global__ __launch_bounds__(256) void prep_kernel(
    const float* __restrict__ w1, const float* __restrict__ w2,
    const float* __restrict__ b2,
    const float* __restrict__ g1, const float* __restrict__ be1,
    const float* __restrict__ m1, const float* __restrict__ v1,
    const float* __restrict__ g2, const float* __restrict__ be2,
    const float* __restrict__ m2, const float* __restrict__ v2,
    float* __restrict__ ws) {
  int tid = blockIdx.x * 256 + threadIdx.x;
  int nthr = gridDim.x * 256;
  for (int i = tid; i < CM * C; i += nthr) {
    int o = i / C, c = i - o * C;
    ws[W1T_OFF + c * CM + o] = w1[i];
  }
  // A fragments (bf16): lane l holds A[row=mt*16+(l&15)][k=ks*32+(l>>4)*8+j]
  {
    ushort* abf = (ushort*)(ws + ABF_OFF);
    for (int i = tid; i < G * 4 * 2 * 64 * 8; i += nthr) {
      int j = i & 7, lane = (i >> 3) & 63, ks = (i >> 9) & 1;
      int mt = (i >> 10) & 3, g = (i >> 12) & 15;
      int m = mt * 16 + (lane & 15);
      int o = ks * 32 + ((lane >> 4) << 3) + j;
      float v = (m < K2) ? w2[(g * K2 + m) * CM + o] : 0.f;
      abf[i] = (ushort)f2bf_rne(v);
    }
  }
  for (int i = tid; i < G * 64; i += nthr) {
    int g = i >> 6, k = i & 63;
    ws[B2P_OFF + i] = (k < K2) ? b2[g * K2 + k] : 0.f;
  }
  if (tid < CM) {
    float inv = g1[tid] * rsqrtf(v1[tid] + EPSV);
    ws[S1_OFF + tid] = inv;
    ws[B1_OFF + tid] = be1[tid] - m1[tid] * inv;
  }
  if (tid < C) {
    float inv = g2[tid] * rsqrtf(v2[tid] + EPSV);
    ws[S2_OFF + tid] = inv;
    ws[B2C_OFF + tid] = be2[tid] - m2[tid] * inv;
  }
  if (tid < 16) ws[ZERO_OFF + tid] = 0.f;
}

// t = relu(bn1(w1 @ x)) stored bf16 [b][tile16][pix256][o64];
// oh==0 blocks also emit xbf (bf16 copy of x) nearly free (x already loaded).
__global__ __launch_bounds__(256) void t_kernel(
    const float* __restrict__ x, float* __restrict__ ws) {
  __shared__ float part[4][32][64];
  int p = threadIdx.x & 63;
  int q = __builtin_amdgcn_readfirstlane(threadIdx.x >> 6);
  int y = blockIdx.x, b = blockIdx.y, oh = blockIdx.z;
  const float* __restrict__ w1T = ws + W1T_OFF + oh * 32;
  ushort* __restrict__ xbf = (ushort*)(ws + XBF_OFF);

  float acc[32];
#pragma unroll
  for (int o = 0; o < 32; ++o) acc[o] = 0.f;
  const float* __restrict__ xrow = x + (((size_t)b * C + q * 64) * H + y) * W;
#pragma unroll 2
  for (int cc = 0; cc < 64; ++cc) {
    float xv = xrow[(size_t)cc * H * W + p];
    if (oh == 0)
      xbf[(size_t)(b * C + q * 64 + cc) * (H * W) + y * W + p] = (ushort)f2bf_rne(xv);
    const float* __restrict__ wr = w1T + (q * 64 + cc) * CM;
#pragma unroll
    for (int o = 0; o < 32; ++o) acc[o] = fmaf(wr[o], xv, acc[o]);
  }
#pragma unroll
  for (int o = 0; o < 32; ++o) part[q][o][p] = acc[o];
  __syncthreads();

  int tile = (y >> 4) * 4 + (p >> 4);
  int pix = (y & 15) * 16 + (p & 15);
  const float* __restrict__ s1 = ws + S1_OFF + oh * 32;
  const float* __restrict__ b1 = ws + B1_OFF + oh * 32;
  float fv[8];
#pragma unroll
  for (int i = 0; i < 8; ++i) {
    int o = q * 8 + i;
    float s = part[0][o][p] + part[1][o][p] + part[2][o][p] + part[3][o][p];
    fv[i] = fmaxf(fmaf(s, s1[o], b1[o]), 0.f);
  }
  uint4 pk;
  pk.x = f2bf_rne(fv[0]) | (f2bf_rne(fv[1]) << 16);
  pk.y = f2bf_rne(fv[2]) | (f2bf_rne(fv[3]) << 16);
  pk.z = f2bf_rne(fv[4]) | (f2bf_rne(fv[5]) << 16);
  pk.w = f2bf_rne(fv[6]) | (f2bf_rne(fv[7]) << 16);
  ushort* tbf = (ushort*)(ws + TBF_OFF);
  size_t idx = (((size_t)(b * 16 + tile) * 256 + pix) * 64) + oh * 32 + q * 8;
  *(uint4*)(tbf + idx) = pk;
}

// per (b, g, 16x16 tile): frag loads -> halo issue (bf16, all 16 ch resident)
// -> MFMA+pack (covers latency) -> ONE barrier -> free-running stencil with
// channel-inner loop (wgt uint4s read once per di, shared across 4 channels).
__global__ __launch_bounds__(256, 3) void inv_kernel(
    const float* __restrict__ ws, float* __restrict__ out) {
  __shared__ uint wgt_u[25][256];        // 25.6 KB [j=k/2][pix]
  __shared__ uint xh[G * HSLOT_U];       // 24.8 KB bf16 halo, 16 ch slabs

  int tid = threadIdx.x;
  int lane = tid & 63;
  int wv = __builtin_amdgcn_readfirstlane(tid >> 6);
  int c16 = lane & 15, q = lane >> 4;
  int tile = blockIdx.x, g = blockIdx.y, b = blockIdx.z;
  int ty = (tile >> 2) * TS, tx = (tile & 3) * TS;
  // stencil mapping: 4 px (quad) x 4 channels per thread
  int py = tid >> 4, pq = (tid >> 2) & 3, chq = tid & 3;

  const ushort* abf = (const ushort*)(ws + ABF_OFF);
  const ushort* tbf = (const ushort*)(ws + TBF_OFF);
  const uint* xbfu = (const uint*)(ws + XBF_OFF);

  // bn2 constants
  float scv[4], bcv[4];
#pragma unroll
  for (int ci = 0; ci < 4; ++ci) {
    int ch = ci * 4 + chq;
    scv[ci] = ws[S2_OFF + g * GC + ch];
    bcv[ci] = ws[B2C_OFF + g * GC + ch];
  }

  // ---- fragment + bias loads (FIRST, so MFMA's wait leaves halo in flight)
  bf16x8 afr[4][2], bfr[4][2];
  f32x4 bias[4];
#pragma unroll
  for (int mt = 0; mt < 4; ++mt) {
#pragma unroll
    for (int ks = 0; ks < 2; ++ks)
      afr[mt][ks] = *(const bf16x8*)(abf + ((g * 8 + mt * 2 + ks) * 64 + lane) * 8);
    bias[mt] = *(const f32x4*)(ws + B2P_OFF + g * 64 + mt * 16 + q * 4);
  }
#pragma unroll
  for (int nt = 0; nt < 4; ++nt) {
    int pix = wv * 64 + nt * 16 + c16;
#pragma unroll
    for (int ks = 0; ks < 2; ++ks)
      bfr[nt][ks] = *(const bf16x8*)(
          tbf + (((size_t)(b * 16 + tile) * 256 + pix) * 64 + ks * 32 + q * 8));
  }

  // ---- halo staging: bf16 u32 pairs; slab row = 16 u32 (24 bf16 cols,
  // global cols tx-4 .. tx+19); 6 gload_lds per channel, 4 ch per wave.
  {
    int hofs[6];
    uint hmask = 0;
#pragma unroll
    for (int i = 0; i < 6; ++i) {
      int s = i * 64 + lane;
      int row = s >> 4, m = s & 15;
      int gy = ty - 3 + row;
      int gx0 = tx - 4 + 2 * m;
      bool v = (m < 12) && (row < 22) && ((unsigned)gy < H) && ((unsigned)gx0 < 63);
      hmask |= (uint)v << i;
      hofs[i] = gy * 32 + (gx0 >> 1);
    }
    const uint* zsrc = (const uint*)(ws + ZERO_OFF);
#pragma unroll
    for (int j = 0; j < 4; ++j) {
      int ch = wv * 4 + j;
      const uint* src_ch = xbfu + (((size_t)(b * C + g * GC + ch) * (H * W)) >> 1);
#pragma unroll
      for (int i = 0; i < 6; ++i) {
        const uint* s = ((hmask >> i) & 1u) ? (src_ch + hofs[i]) : zsrc;
        gload_lds4(s, &xh[ch * HSLOT_U + i * 64]);
      }
    }
  }

  // ---- MFMA GEMM + pack into wgt_u[25][256] ------------------------------
#pragma unroll
  for (int nt = 0; nt < 4; ++nt) {
    f32x4 a[4];
#pragma unroll
    for (int mt = 0; mt < 4; ++mt) a[mt] = bias[mt];
#pragma unroll
    for (int ks = 0; ks < 2; ++ks)
#pragma unroll
      for (int mt = 0; mt < 4; ++mt)
        a[mt] = __builtin_amdgcn_mfma_f32_16x16x32_bf16(afr[mt][ks], bfr[nt][ks],
                                                        a[mt], 0, 0, 0);
    int pix = wv * 64 + nt * 16 + c16;
#pragma unroll
    for (int mt = 0; mt < 4; ++mt) {
      uint lo = f2bf_rne(a[mt][0]) | (f2bf_rne(a[mt][1]) << 16);
      uint hi = f2bf_rne(a[mt][2]) | (f2bf_rne(a[mt][3]) << 16);
      int j0v = mt * 8 + q * 2;
      if (j0v < 25) wgt_u[j0v][pix] = lo;
      if (j0v + 1 < 25) wgt_u[j0v + 1][pix] = hi;
    }
  }

  // ---- ONE barrier: halo loads + pack writes all complete ----------------
  asm volatile("s_waitcnt vmcnt(0) lgkmcnt(0)" ::: "memory");
  __builtin_amdgcn_s_barrier();
  __builtin_amdgcn_sched_barrier(0);

  // ---- stencil: di outer (wgt once), channels inner ----------------------
  f32x4 acc[4];
#pragma unroll
  for (int ci = 0; ci < 4; ++ci) acc[ci] = (f32x4){0.f, 0.f, 0.f, 0.f};

#pragma unroll
  for (int di = 0; di < KS; ++di) {
    const int j0 = (di * KS) >> 1;
    uint4 wq[4];
#pragma unroll
    for (int m = 0; m < 4; ++m)
      wq[m] = *(const uint4*)&wgt_u[j0 + m][py * 16 + pq * 4];
    // unpack 28 weights (px i, dj) once; shared by the 4 channels
    float wf[28];
#pragma unroll
    for (int dj = 0; dj < KS; ++dj) {
      const int k = di * KS + dj;
      const int m = (k >> 1) - j0, hf = k & 1;
#pragma unroll
      for (int i = 0; i < 4; ++i) {
        uint u = (&wq[m].x)[i];
        wf[dj * 4 + i] = __uint_as_float(hf ? (u & 0xffff0000u) : (u << 16));
      }
    }
    int rowb = (py + di) * 16 + 2 * pq;
#pragma unroll
    for (int ci = 0; ci < 4; ++ci) {
      int ch = ci * 4 + chq;
      const uint* sl = &xh[ch * HSLOT_U + rowb];
      uint2 r0 = *(const uint2*)(sl);
      uint2 r1 = *(const uint2*)(sl + 2);
      uint2 r2 = *(const uint2*)(sl + 4);
      // bf16 slab idx 4pq+t ; need t = 1..10
      float hv[12];
      hv[1] = __uint_as_float(r0.x & 0xffff0000u);
      hv[2] = __uint_as_float(r0.y << 16);
      hv[3] = __uint_as_float(r0.y & 0xffff0000u);
      hv[4] = __uint_as_float(r1.x << 16);
      hv[5] = __uint_as_float(r1.x & 0xffff0000u);
      hv[6] = __uint_as_float(r1.y << 16);
      hv[7] = __uint_as_float(r1.y & 0xffff0000u);
      hv[8] = __uint_as_float(r2.x << 16);
      hv[9] = __uint_as_float(r2.x & 0xffff0000u);
      hv[10] = __uint_as_float(r2.y << 16);
#pragma unroll
      for (int dj = 0; dj < KS; ++dj)
#pragma unroll
        for (int i = 0; i < 4; ++i)
          acc[ci][i] = fmaf(hv[i + dj + 1], wf[dj * 4 + i], acc[ci][i]);
    }
  }

  // ---- bn2 + relu + store ------------------------------------------------
#pragma unroll
  for (int ci = 0; ci < 4; ++ci) {
    int ch = ci * 4 + chq;
    float4 o4;
    o4.x = fmaxf(fmaf(acc[ci][0], scv[ci], bcv[ci]), 0.f);
    o4.y = fmaxf(fmaf(acc[ci][1], scv[ci], bcv[ci]), 0.f);
    o4.z = fmaxf(fmaf(acc[ci][2], scv[ci], bcv[ci]), 0.f);
    o4.w = fmaxf(fmaf(acc[ci][3], scv[ci], bcv[ci]), 0.f);
    *(float4*)(out + (((size_t)b * C + g * GC + ch) * H + ty + py) * W + tx + pq * 4) = o4;
  }
}

extern "C" void kernel_launch(void* const* d_in, const int* in_sizes, int n_in,
                              void* d_out, int out_size, void* d_ws, size_t ws_size,
                              hipStream_t stream) {
  const float* x   = (const float*)d_in[0];
  const float* w1  = (const float*)d_in[1];
  const float* g1  = (const float*)d_in[2];
  const float* be1 = (const float*)d_in[3];
  const float* m1  = (const float*)d_in[4];
  const float* v1  = (const float*)d_in[5];
  const float* w2  = (const float*)d_in[6];
  const float* b2  = (const float*)d_in[7];
  const float* g2  = (const float*)d_in[8];
  const float* be2 = (const float*)d_in[9];
  const float* m2  = (const float*)d_in[10];
  const float* v2  = (const float*)d_in[11];
  float* outp = (float*)d_out;
  float* ws = (float*)d_ws;

  prep_kernel<<<dim3(64), dim3(256), 0, stream>>>(w1, w2, b2, g1, be1, m1, v1,
                                                  g2, be2, m2, v2, ws);
  t_kernel<<<dim3(H, BN, 2), dim3(256), 0, stream>>>(x, ws);
  inv_kernel<<<dim3(16, G, BN), dim3(256), 0, stream>>>(ws, outp);
}